// Round 4
// baseline (326.733 us; speedup 1.0000x reference)
//
#include <hip/hip_runtime.h>
#include <stdint.h>

// ---------------------------------------------------------------------------
// GCN 4-layer encoder. N=50000 nodes, E=1.6M edges. fp32 in/out, int32 edges.
// Round 17 -> 18:
//  * XCD COLUMN AFFINITY for pulls: split each pull block into (node-block,
//    feature-half) with half = blockIdx.x & 1. Block->XCD is round-robin
//    (lid % 8), so even XCDs only ever read feature bytes [0,128) of every
//    payload row, odd XCDs bytes [128,256) -> per-XCD payload stream halves.
//    r17 evidence: pull<128> FETCH=125MB vs 102MB compulsory (= payload x
//    8 XCDs) filled at ~370 GB/s/XCD (2.6 lines/cyc/XCD) = the binder; the
//    only remaining lever is the compulsory term itself. Predicted FETCH
//    125->~85MB (51 payload + 19 pcsr[now read by 2 XCDs] + 13 self).
//    Work partition is bijective; per-(node,feature) sum order unchanged ->
//    bitwise-identical output. D=32 pull (1-line rows) not split.
//  * 16-bin counting-sorted rows (r17), two-phase bucketed CSR build (r15),
//    pre-scaled pull payloads (r14), bf16 MFMA GEMMs, L1 via A(xW)=(Ax)W.
// ---------------------------------------------------------------------------

#define NN      50000
#define CAP     96           // padded in-edge slots per node; deg~Poisson(32)
#define BSZ     256          // nodes per bucket
#define NB      196          // ceil(NN/BSZ)
#define NSLICEA 256          // phase-A edge slices (== phase-B block threads)
#define CAPSEG  96           // per-(slice,bucket) segment capacity; lam~32
#define NBIN    16           // src bins (src>>12); window ~1MB of payload
#define LPAD    98           // lrow stride in ushorts (49 dwords, bank-spread)

typedef int   iv4   __attribute__((ext_vector_type(4)));
typedef short bfv8  __attribute__((ext_vector_type(8)));   // 8 bf16 = A/B frag
typedef float fv4   __attribute__((ext_vector_type(4)));   // 4 f32  = C/D frag

__device__ __forceinline__ float bflo(uint32_t u) {  // low ushort -> fp32
    uint32_t b = u << 16; float f; __builtin_memcpy(&f, &b, 4); return f;
}
__device__ __forceinline__ float bfhi(uint32_t u) {  // high ushort -> fp32
    uint32_t b = u & 0xffff0000u; float f; __builtin_memcpy(&f, &b, 4); return f;
}
__device__ __forceinline__ unsigned short f2bf(float f) {  // RNE
    uint32_t u; __builtin_memcpy(&u, &f, 4);
    return (unsigned short)((u + 0x7fffu + ((u >> 16) & 1u)) >> 16);
}
__device__ __forceinline__ uint32_t packbf(float lo, float hi) {
    return (uint32_t)f2bf(lo) | ((uint32_t)f2bf(hi) << 16);
}

// fp32 -> bf16 with per-row dinv scaling (layer-1 pull input), 4 elems/thread
__global__ void k_b2fs(unsigned short* __restrict__ out, const float* __restrict__ in,
                       const float* __restrict__ dinv, int n4, int lgq) {
    int t = blockIdx.x * blockDim.x + threadIdx.x;
    if (t >= n4) return;
    float w = dinv[t >> lgq];
    float4 v = reinterpret_cast<const float4*>(in)[t];
    ushort4 o;
    o.x = f2bf(v.x * w); o.y = f2bf(v.y * w);
    o.z = f2bf(v.z * w); o.w = f2bf(v.w * w);
    reinterpret_cast<ushort4*>(out)[t] = o;
}

// W[din,dout] fp32 -> Wt[din/32][dout][32] bf16  (MFMA B-operand native)
__global__ void k_wt(unsigned short* __restrict__ wt, const float* __restrict__ W,
                     int din, int dout) {
    int t = blockIdx.x * blockDim.x + threadIdx.x;
    int total = (din / 32) * dout;
    if (t >= total) return;
    int kc = t / dout, n = t - kc * dout;
    unsigned short* o = wt + (long)t * 32;
#pragma unroll
    for (int kk = 0; kk < 32; ++kk) o[kk] = f2bf(W[(kc * 32 + kk) * dout + n]);
}

// ---- CSR build phase A: bucket edges by dst>>8 into slice-private segments.
// val = (src<<8) | (dst&255); 24 bits (src<50000<2^16). No global atomics.
__global__ __launch_bounds__(256) void k_bucket(uint32_t* __restrict__ seg,
                                                int* __restrict__ cnts,
                                                const int* __restrict__ src,
                                                const int* __restrict__ dst,
                                                int E) {
    __shared__ int cnt[NB];
    const int slice = blockIdx.x;
    for (int i = threadIdx.x; i < NB; i += 256) cnt[i] = 0;
    __syncthreads();
    int per = (E + NSLICEA - 1) / NSLICEA;
    per = (per + 3) & ~3;
    const int e0 = slice * per;
    uint32_t* const segp = seg + (long)slice * NB * CAPSEG;
    if (e0 < E) {
        const int e1 = (e0 + per < E) ? e0 + per : E;
        const int nv = (e1 - e0) & ~3;
        for (int t = e0 + (int)threadIdx.x * 4; t + 4 <= e0 + nv; t += 256 * 4) {
            iv4 dd = __builtin_nontemporal_load((const iv4*)(dst + t));
            iv4 ss = __builtin_nontemporal_load((const iv4*)(src + t));
#pragma unroll
            for (int q = 0; q < 4; ++q) {
                int d = dd[q];
                int b = d >> 8;
                uint32_t val = ((uint32_t)ss[q] << 8) | (uint32_t)(d & 255);
                int slot = atomicAdd(&cnt[b], 1);          // LDS atomic
                if (slot < CAPSEG) segp[b * CAPSEG + slot] = val;
            }
        }
        int tt = e0 + nv + (int)threadIdx.x;
        if (tt < e1) {
            int d = __builtin_nontemporal_load(dst + tt);
            int s = __builtin_nontemporal_load(src + tt);
            int b = d >> 8;
            uint32_t val = ((uint32_t)s << 8) | (uint32_t)(d & 255);
            int slot = atomicAdd(&cnt[b], 1);
            if (slot < CAPSEG) segp[b * CAPSEG + slot] = val;
        }
    }
    __syncthreads();
    for (int i = threadIdx.x; i < NB; i += 256)
        cnts[slice * NB + i] = (cnt[i] < CAPSEG) ? cnt[i] : CAPSEG;
}

// ---- CSR build phase B: one block per bucket; two-pass binned drain builds
// each row coarsely src-sorted (16 bins by src>>12), then coalesced writeback.
__global__ __launch_bounds__(256) void k_build(unsigned short* __restrict__ pcsr,
                                               int* __restrict__ cur,
                                               const uint32_t* __restrict__ seg,
                                               const int* __restrict__ cnts,
                                               int N) {
    __shared__ unsigned short lrow[BSZ][LPAD];   // 50.2KB
    __shared__ int bcnt[BSZ][NBIN + 1];          // 17.4KB, stride 17 dwords
    __shared__ int ldeg[BSZ];
    const int b = blockIdx.x;
    for (int i = threadIdx.x; i < BSZ * (NBIN + 1); i += 256)
        ((int*)bcnt)[i] = 0;
    __syncthreads();

    const int slice = threadIdx.x;               // 256 threads == NSLICEA
    const int n = cnts[slice * NB + b];
    const uint32_t* sp = seg + ((long)slice * NB + b) * CAPSEG;

    // pass 1: count per-(row,bin)
    for (int i = 0; i < n; ++i) {
        uint32_t val = sp[i];
        int d = (int)(val & 255u);
        int s = (int)(val >> 8);
        atomicAdd(&bcnt[d][s >> 12], 1);
    }
    __syncthreads();

    // per-row exclusive prefix over bins (thread r = row r; stride 17 dwords
    // -> conflict-free). ldeg = total.
    {
        const int r = threadIdx.x;
        int acc = 0;
#pragma unroll
        for (int k = 0; k < NBIN; ++k) {
            int c = bcnt[r][k];
            bcnt[r][k] = acc;
            acc += c;
        }
        ldeg[r] = acc;
    }
    __syncthreads();

    // pass 2: re-drain (L2-warm) into binned slots
    for (int i = 0; i < n; ++i) {
        uint32_t val = sp[i];
        int d = (int)(val & 255u);
        int s = (int)(val >> 8);
        int slot = atomicAdd(&bcnt[d][s >> 12], 1);
        if (slot < CAP) lrow[d][slot] = (unsigned short)s;
    }
    __syncthreads();

    const int node0 = b * BSZ;
    int nrows = N - node0;
    if (nrows > BSZ) nrows = BSZ;
    // writeback: 48 dwords/row (CAP ushorts), LDS stride 49 dwords.
    const int total = nrows * (CAP / 2);
    for (int idx = threadIdx.x; idx < total; idx += 256) {
        int r = idx / (CAP / 2);
        int c = idx - r * (CAP / 2);
        ((uint32_t*)(pcsr + (long)(node0 + r) * CAP))[c] =
            ((const uint32_t*)lrow[r])[c];
    }
    for (int r = threadIdx.x; r < nrows; r += 256) cur[node0 + r] = ldeg[r];
}

__global__ void k_dinv(float* __restrict__ dinv, const int* __restrict__ cur, int n) {
    int t = blockIdx.x * blockDim.x + threadIdx.x;
    if (t < n) dinv[t] = 1.0f / sqrtf((float)cur[t] + 1.0f);
}

// Pull aggregation over PRE-SCALED bf16 payload H' (= H*dinv), fp32 accumulate:
//   out[i,:] = dinv_i * (H'[i,:] + sum_{e: dst=i} H'[src_e,:])  (+bias, relu)
// thread = (node, 8 features); 16B uint4 gathers; 4-edge unroll; pure adds.
// Rows are coarsely src-sorted -> gathers stream ascending through payload.
// SPLIT: feature-half chosen by blockIdx parity -> per-XCD payload stream
// halves (block->XCD is round-robin lid%8; even XCDs get half 0).
template <int D, int BR, int OUTBF, int SPLIT>
__global__ __launch_bounds__(256) void k_pullq(void* __restrict__ outv,
                                               const unsigned short* __restrict__ Hb,
                                               const unsigned short* __restrict__ pcsr,
                                               const int* __restrict__ deg,
                                               const float* __restrict__ dinv,
                                               const float* __restrict__ bias,
                                               int n) {
    constexpr int TPN = D / 8;                    // uint4 slots per row
    constexpr int TPH = SPLIT ? TPN / 2 : TPN;    // threads per node
    constexpr int NPB = 256 / TPH;                // nodes per block
    const int lid  = blockIdx.x;
    const int half = SPLIT ? (lid & 1) : 0;
    const int nb   = SPLIT ? (lid >> 1) : lid;
    const int node = nb * NPB + threadIdx.x / TPH;
    const int f8   = half * TPH + threadIdx.x % TPH;
    if (node >= n) return;
    const float wd = dinv[node];
    const uint4* __restrict__ Hv = (const uint4*)Hb;  // 8 bf16 per uint4
    uint4 ps = Hv[(long)node * TPN + f8];             // self term, pre-scaled
    float a0 = bflo(ps.x), a1 = bfhi(ps.x);
    float a2 = bflo(ps.y), a3 = bfhi(ps.y);
    float a4 = bflo(ps.z), a5 = bfhi(ps.z);
    float a6 = bflo(ps.w), a7 = bfhi(ps.w);
    int dg = deg[node];
    if (dg > CAP) dg = CAP;
    const unsigned short* __restrict__ row = pcsr + (long)node * CAP;
    int j = 0;
    for (; j + 4 <= dg; j += 4) {
        ushort4 ii = *(const ushort4*)(row + j);
        uint4 p0 = Hv[(long)ii.x * TPN + f8];
        uint4 p1 = Hv[(long)ii.y * TPN + f8];
        uint4 p2 = Hv[(long)ii.z * TPN + f8];
        uint4 p3 = Hv[(long)ii.w * TPN + f8];
        a0 += bflo(p0.x) + bflo(p1.x) + bflo(p2.x) + bflo(p3.x);
        a1 += bfhi(p0.x) + bfhi(p1.x) + bfhi(p2.x) + bfhi(p3.x);
        a2 += bflo(p0.y) + bflo(p1.y) + bflo(p2.y) + bflo(p3.y);
        a3 += bfhi(p0.y) + bfhi(p1.y) + bfhi(p2.y) + bfhi(p3.y);
        a4 += bflo(p0.z) + bflo(p1.z) + bflo(p2.z) + bflo(p3.z);
        a5 += bfhi(p0.z) + bfhi(p1.z) + bfhi(p2.z) + bfhi(p3.z);
        a6 += bflo(p0.w) + bflo(p1.w) + bflo(p2.w) + bflo(p3.w);
        a7 += bfhi(p0.w) + bfhi(p1.w) + bfhi(p2.w) + bfhi(p3.w);
    }
    for (; j < dg; ++j) {
        uint4 p = Hv[(long)row[j] * TPN + f8];
        a0 += bflo(p.x); a1 += bfhi(p.x);
        a2 += bflo(p.y); a3 += bfhi(p.y);
        a4 += bflo(p.z); a5 += bfhi(p.z);
        a6 += bflo(p.w); a7 += bfhi(p.w);
    }
    a0 *= wd; a1 *= wd; a2 *= wd; a3 *= wd;
    a4 *= wd; a5 *= wd; a6 *= wd; a7 *= wd;
    if (BR) {
        float4 b0 = ((const float4*)bias)[2 * f8];
        float4 b1 = ((const float4*)bias)[2 * f8 + 1];
        a0 = fmaxf(a0 + b0.x, 0.f); a1 = fmaxf(a1 + b0.y, 0.f);
        a2 = fmaxf(a2 + b0.z, 0.f); a3 = fmaxf(a3 + b0.w, 0.f);
        a4 = fmaxf(a4 + b1.x, 0.f); a5 = fmaxf(a5 + b1.y, 0.f);
        a6 = fmaxf(a6 + b1.z, 0.f); a7 = fmaxf(a7 + b1.w, 0.f);
    }
    if (OUTBF) {
        uint4 o;
        o.x = packbf(a0, a1); o.y = packbf(a2, a3);
        o.z = packbf(a4, a5); o.w = packbf(a6, a7);
        ((uint4*)outv)[(long)node * TPN + f8] = o;
    } else {
        float4 o0; o0.x = a0; o0.y = a1; o0.z = a2; o0.w = a3;
        float4 o1; o1.x = a4; o1.y = a5; o1.z = a6; o1.w = a7;
        ((float4*)outv)[(long)node * (D / 4) + 2 * f8] = o0;
        ((float4*)outv)[(long)node * (D / 4) + 2 * f8 + 1] = o1;
    }
}

// MFMA GEMM: out[N,dout] = Xb[N,DIN](bf16) @ W (via Wt packing), fp32 acc.
// wave = 16 rows x NT*16 cols; block = 4 waves = 64 rows. No LDS.
// SCALE: multiply output row m by dinv[m] (pre-scaling for the next pull).
template <int DIN, int NT, int BIAS_RELU, int OUTBF, int SCALE>
__global__ __launch_bounds__(256) void k_mm(const unsigned short* __restrict__ Xb,
                                            const unsigned short* __restrict__ Wt,
                                            const float* __restrict__ bias,
                                            const float* __restrict__ dinv,
                                            void* __restrict__ outv,
                                            int N, int dout) {
    constexpr int KI = DIN / 32;
    const int lane = threadIdx.x & 63;
    const int wv   = threadIdx.x >> 6;
    const int m0   = blockIdx.x * 64 + wv * 16;
    const int n0   = blockIdx.y * (NT * 16);
    const int l15  = lane & 15;
    const int quad = lane >> 4;

    int mrow = m0 + l15;
    if (mrow >= N) mrow = N - 1;                     // clamped loads; stores guarded
    const unsigned short* xp = Xb + (long)mrow * DIN + quad * 8;
    const unsigned short* wp = Wt + (long)(n0 + l15) * 32 + quad * 8;

    fv4 acc[NT];
#pragma unroll
    for (int t = 0; t < NT; ++t) acc[t] = (fv4){0.f, 0.f, 0.f, 0.f};

#pragma unroll
    for (int kc = 0; kc < KI; ++kc) {
        bfv8 a = *(const bfv8*)(xp + kc * 32);
#pragma unroll
        for (int t = 0; t < NT; ++t) {
            bfv8 b = *(const bfv8*)(wp + (long)kc * dout * 32 + t * 16 * 32);
            acc[t] = __builtin_amdgcn_mfma_f32_16x16x32_bf16(a, b, acc[t], 0, 0, 0);
        }
    }

    float sc[4];
#pragma unroll
    for (int r = 0; r < 4; ++r) {
        int m = m0 + quad * 4 + r;
        sc[r] = SCALE ? dinv[(m < N) ? m : (N - 1)] : 1.0f;
    }

#pragma unroll
    for (int t = 0; t < NT; ++t) {
        const int col = n0 + t * 16 + l15;
        float bb = BIAS_RELU ? bias[col] : 0.f;
#pragma unroll
        for (int r = 0; r < 4; ++r) {
            int m = m0 + quad * 4 + r;
            if (m < N) {
                float v = acc[t][r];
                if (BIAS_RELU) v = fmaxf(v + bb, 0.f);
                if (SCALE) v *= sc[r];
                if (OUTBF)
                    ((unsigned short*)outv)[(long)m * dout + col] = f2bf(v);
                else
                    ((float*)outv)[(long)m * dout + col] = v;
            }
        }
    }
}

extern "C" void kernel_launch(void* const* d_in, const int* in_sizes, int n_in,
                              void* d_out, int out_size, void* d_ws, size_t ws_size,
                              hipStream_t stream) {
    const int N = NN;
    const int E = in_sizes[1] / 2;

    const float* x  = (const float*)d_in[0];
    const int* ei   = (const int*)d_in[1];
    const int* src  = ei;
    const int* dst  = ei + E;
    const float* W1 = (const float*)d_in[2];
    const float* b1 = (const float*)d_in[3];
    const float* W2 = (const float*)d_in[4];
    const float* b2 = (const float*)d_in[5];
    const float* W3 = (const float*)d_in[6];
    const float* b3 = (const float*)d_in[7];
    const float* W4 = (const float*)d_in[8];
    const float* b4 = (const float*)d_in[9];

    float* dinv = (float*)d_ws;                       // N f32
    int*   cur  = (int*)(dinv + N);                   // N i32
    unsigned short* U    = (unsigned short*)(cur + N);        // N*256 bf16
    unsigned short* V    = U + (long)N * 256;                 // N*256 bf16
    unsigned short* pcsr = V + (long)N * 256;                 // N*CAP ushort
    unsigned short* Wt1  = pcsr + (long)N * CAP;              // 128*256
    unsigned short* Wt2  = Wt1 + 128 * 256;                   // 256*128
    unsigned short* Wt3  = Wt2 + 256 * 128;                   // 128*64
    unsigned short* Wt4  = Wt3 + 128 * 64;                    // 64*32

    // CSR-build scratch: lives inside U (dead until k_b2fs overwrites it).
    // seg: 256 slices x 196 buckets x 96 cap x 4B = 19.27MB  (U = 25.6MB)
    uint32_t* seg  = (uint32_t*)U;
    int*      cnts = (int*)(seg + (long)NSLICEA * NB * CAPSEG);  // 256*196 i32

    (void)n_in; (void)out_size; (void)ws_size;

    const int BT = 256;
    auto g = [&](int n) { return (n + BT - 1) / BT; };
    const int GX = (N + 63) / 64;                     // 782 row-blocks

    // ---- CSR build (2-phase bucketed, binned rows) + conversions
    k_bucket<<<NSLICEA, 256, 0, stream>>>(seg, cnts, src, dst, E);
    k_build<<<NB, 256, 0, stream>>>(pcsr, cur, seg, cnts, N);
    k_dinv<<<g(N), BT, 0, stream>>>(dinv, cur, N);
    k_b2fs<<<g(N * 128 / 4), BT, 0, stream>>>(U, x, dinv, N * 128 / 4, 5);
    k_wt<<<g(4 * 256), BT, 0, stream>>>(Wt1, W1, 128, 256);
    k_wt<<<g(8 * 128), BT, 0, stream>>>(Wt2, W2, 256, 128);
    k_wt<<<g(4 * 64), BT, 0, stream>>>(Wt3, W3, 128, 64);
    k_wt<<<g(2 * 32), BT, 0, stream>>>(Wt4, W4, 64, 32);

    // split-pull grids: 2 x node-blocks (NPB = 256/(D/16))
    const int GP128 = 2 * ((N + 31) / 32);            // D=128: NPB=32
    const int GP64  = 2 * ((N + 63) / 64);            // D=64:  NPB=64

    // ---- Layer 1: P0b = Prop(x') [N,128] -> V; H1b = relu(P0b@W1+b1) [N,256] -> U
    k_pullq<128, 0, 1, 1><<<GP128, 256, 0, stream>>>(V, U, pcsr, cur, dinv, nullptr, N);
    k_mm<128, 4, 1, 1, 0><<<dim3(GX, 4), 256, 0, stream>>>(V, Wt1, b1, dinv, U, N, 256);

    // ---- Layer 2: T2' = (H1b@W2)*dinv [N,128] -> V; H2b = relu(Prop+b2) -> U
    k_mm<256, 4, 0, 1, 1><<<dim3(GX, 2), 256, 0, stream>>>(U, Wt2, nullptr, dinv, V, N, 128);
    k_pullq<128, 1, 1, 1><<<GP128, 256, 0, stream>>>(U, V, pcsr, cur, dinv, b2, N);

    // ---- Layer 3: T3' = (H2b@W3)*dinv [N,64] -> V; H3b = relu(Prop+b3) -> U
    k_mm<128, 4, 0, 1, 1><<<dim3(GX, 1), 256, 0, stream>>>(U, Wt3, nullptr, dinv, V, N, 64);
    k_pullq<64, 1, 1, 1><<<GP64, 256, 0, stream>>>(U, V, pcsr, cur, dinv, b3, N);

    // ---- Layer 4: T4' = (H3b@W4)*dinv [N,32] -> V; out = relu(Prop+b4) fp32
    k_mm<64, 2, 0, 1, 1><<<dim3(GX, 1), 256, 0, stream>>>(U, Wt4, nullptr, dinv, V, N, 32);
    k_pullq<32, 1, 0, 0><<<(N + 63) / 64, 256, 0, stream>>>(d_out, V, pcsr, cur, dinv, b4, N);
}

// Round 5
// 308.562 us; speedup vs baseline: 1.0589x; 1.0589x over previous
//
#include <hip/hip_runtime.h>
#include <stdint.h>

// ---------------------------------------------------------------------------
// GCN 4-layer encoder. N=50000 nodes, E=1.6M edges. fp32 in/out, int32 edges.
// Round 18 -> 19:
//  * r18 post-mortem: XCD feature-half split was neutral-to-negative (322->
//    327us) -> REVERTED (either block->XCD mapping isn't lid%8 here, or the
//    binder isn't per-XCD HBM fill; mechanism unconfirmed, pcsr cost real).
//  * LAUNCH-COUNT CUT: accounting says ~190-200us of kernel time vs 322us
//    wall -> ~8us/launch of gap over 16 launches. k_dinv + k_b2fs + 4x k_wt
//    all depend only on k_build's cur + inputs -> fused into ONE k_prep
//    (block-range branching; b2fs recomputes 1/sqrtf(cur+1) inline, bitwise
//    identical expression). 16 launches -> 11.
//  * 16-bin counting-sorted rows (r17), two-phase bucketed CSR build (r15),
//    pre-scaled pull payloads (r14), bf16 MFMA GEMMs, L1 via A(xW)=(Ax)W.
// ---------------------------------------------------------------------------

#define NN      50000
#define CAP     96           // padded in-edge slots per node; deg~Poisson(32)
#define BSZ     256          // nodes per bucket
#define NB      196          // ceil(NN/BSZ)
#define NSLICEA 256          // phase-A edge slices (== phase-B block threads)
#define CAPSEG  96           // per-(slice,bucket) segment capacity; lam~32
#define NBIN    16           // src bins (src>>12); window ~1MB of payload
#define LPAD    98           // lrow stride in ushorts (49 dwords, bank-spread)

// k_prep block ranges (compile-time; N fixed)
#define PREP_DINV_B   196                      // ceil(NN/256)
#define PREP_B2FS_B   6250                     // NN*128/4/256
#define PREP_WT_T     2368                     // 1024+1024+256+64 pack threads
#define PREP_WT_B     10                       // ceil(2368/256)

typedef int   iv4   __attribute__((ext_vector_type(4)));
typedef short bfv8  __attribute__((ext_vector_type(8)));   // 8 bf16 = A/B frag
typedef float fv4   __attribute__((ext_vector_type(4)));   // 4 f32  = C/D frag

__device__ __forceinline__ float bflo(uint32_t u) {  // low ushort -> fp32
    uint32_t b = u << 16; float f; __builtin_memcpy(&f, &b, 4); return f;
}
__device__ __forceinline__ float bfhi(uint32_t u) {  // high ushort -> fp32
    uint32_t b = u & 0xffff0000u; float f; __builtin_memcpy(&f, &b, 4); return f;
}
__device__ __forceinline__ unsigned short f2bf(float f) {  // RNE
    uint32_t u; __builtin_memcpy(&u, &f, 4);
    return (unsigned short)((u + 0x7fffu + ((u >> 16) & 1u)) >> 16);
}
__device__ __forceinline__ uint32_t packbf(float lo, float hi) {
    return (uint32_t)f2bf(lo) | ((uint32_t)f2bf(hi) << 16);
}

// ---- CSR build phase A: bucket edges by dst>>8 into slice-private segments.
// val = (src<<8) | (dst&255); 24 bits (src<50000<2^16). No global atomics.
__global__ __launch_bounds__(256) void k_bucket(uint32_t* __restrict__ seg,
                                                int* __restrict__ cnts,
                                                const int* __restrict__ src,
                                                const int* __restrict__ dst,
                                                int E) {
    __shared__ int cnt[NB];
    const int slice = blockIdx.x;
    for (int i = threadIdx.x; i < NB; i += 256) cnt[i] = 0;
    __syncthreads();
    int per = (E + NSLICEA - 1) / NSLICEA;
    per = (per + 3) & ~3;
    const int e0 = slice * per;
    uint32_t* const segp = seg + (long)slice * NB * CAPSEG;
    if (e0 < E) {
        const int e1 = (e0 + per < E) ? e0 + per : E;
        const int nv = (e1 - e0) & ~3;
        for (int t = e0 + (int)threadIdx.x * 4; t + 4 <= e0 + nv; t += 256 * 4) {
            iv4 dd = __builtin_nontemporal_load((const iv4*)(dst + t));
            iv4 ss = __builtin_nontemporal_load((const iv4*)(src + t));
#pragma unroll
            for (int q = 0; q < 4; ++q) {
                int d = dd[q];
                int b = d >> 8;
                uint32_t val = ((uint32_t)ss[q] << 8) | (uint32_t)(d & 255);
                int slot = atomicAdd(&cnt[b], 1);          // LDS atomic
                if (slot < CAPSEG) segp[b * CAPSEG + slot] = val;
            }
        }
        int tt = e0 + nv + (int)threadIdx.x;
        if (tt < e1) {
            int d = __builtin_nontemporal_load(dst + tt);
            int s = __builtin_nontemporal_load(src + tt);
            int b = d >> 8;
            uint32_t val = ((uint32_t)s << 8) | (uint32_t)(d & 255);
            int slot = atomicAdd(&cnt[b], 1);
            if (slot < CAPSEG) segp[b * CAPSEG + slot] = val;
        }
    }
    __syncthreads();
    for (int i = threadIdx.x; i < NB; i += 256)
        cnts[slice * NB + i] = (cnt[i] < CAPSEG) ? cnt[i] : CAPSEG;
}

// ---- CSR build phase B: one block per bucket; two-pass binned drain builds
// each row coarsely src-sorted (16 bins by src>>12), then coalesced writeback.
__global__ __launch_bounds__(256) void k_build(unsigned short* __restrict__ pcsr,
                                               int* __restrict__ cur,
                                               const uint32_t* __restrict__ seg,
                                               const int* __restrict__ cnts,
                                               int N) {
    __shared__ unsigned short lrow[BSZ][LPAD];   // 50.2KB
    __shared__ int bcnt[BSZ][NBIN + 1];          // 17.4KB, stride 17 dwords
    __shared__ int ldeg[BSZ];
    const int b = blockIdx.x;
    for (int i = threadIdx.x; i < BSZ * (NBIN + 1); i += 256)
        ((int*)bcnt)[i] = 0;
    __syncthreads();

    const int slice = threadIdx.x;               // 256 threads == NSLICEA
    const int n = cnts[slice * NB + b];
    const uint32_t* sp = seg + ((long)slice * NB + b) * CAPSEG;

    // pass 1: count per-(row,bin)
    for (int i = 0; i < n; ++i) {
        uint32_t val = sp[i];
        int d = (int)(val & 255u);
        int s = (int)(val >> 8);
        atomicAdd(&bcnt[d][s >> 12], 1);
    }
    __syncthreads();

    // per-row exclusive prefix over bins (thread r = row r; stride 17 dwords
    // -> conflict-free). ldeg = total.
    {
        const int r = threadIdx.x;
        int acc = 0;
#pragma unroll
        for (int k = 0; k < NBIN; ++k) {
            int c = bcnt[r][k];
            bcnt[r][k] = acc;
            acc += c;
        }
        ldeg[r] = acc;
    }
    __syncthreads();

    // pass 2: re-drain (L2-warm) into binned slots
    for (int i = 0; i < n; ++i) {
        uint32_t val = sp[i];
        int d = (int)(val & 255u);
        int s = (int)(val >> 8);
        int slot = atomicAdd(&bcnt[d][s >> 12], 1);
        if (slot < CAP) lrow[d][slot] = (unsigned short)s;
    }
    __syncthreads();

    const int node0 = b * BSZ;
    int nrows = N - node0;
    if (nrows > BSZ) nrows = BSZ;
    // writeback: 48 dwords/row (CAP ushorts), LDS stride 49 dwords.
    const int total = nrows * (CAP / 2);
    for (int idx = threadIdx.x; idx < total; idx += 256) {
        int r = idx / (CAP / 2);
        int c = idx - r * (CAP / 2);
        ((uint32_t*)(pcsr + (long)(node0 + r) * CAP))[c] =
            ((const uint32_t*)lrow[r])[c];
    }
    for (int r = threadIdx.x; r < nrows; r += 256) cur[node0 + r] = ldeg[r];
}

// W[din,dout] fp32 -> Wt[din/32][dout][32] bf16 (MFMA B-operand), one elem/t
__device__ __forceinline__ void wt_pack(unsigned short* __restrict__ wt,
                                        const float* __restrict__ W,
                                        int dout, int t) {
    int kc = t / dout, n = t - kc * dout;
    unsigned short* o = wt + (long)t * 32;
#pragma unroll
    for (int kk = 0; kk < 32; ++kk) o[kk] = f2bf(W[(kc * 32 + kk) * dout + n]);
}

// ---- Fused prep: dinv + b2fs(x->U bf16, pre-scaled) + all 4 Wt packs.
// All depend only on k_build's cur + kernel inputs -> one launch.
__global__ __launch_bounds__(256) void k_prep(float* __restrict__ dinv,
                                              const int* __restrict__ cur,
                                              unsigned short* __restrict__ U,
                                              const float* __restrict__ x,
                                              unsigned short* __restrict__ Wt1,
                                              const float* __restrict__ W1,
                                              unsigned short* __restrict__ Wt2,
                                              const float* __restrict__ W2,
                                              unsigned short* __restrict__ Wt3,
                                              const float* __restrict__ W3,
                                              unsigned short* __restrict__ Wt4,
                                              const float* __restrict__ W4) {
    const int b = blockIdx.x;
    if (b < PREP_DINV_B) {
        int t = b * 256 + threadIdx.x;
        if (t < NN) dinv[t] = 1.0f / sqrtf((float)cur[t] + 1.0f);
    } else if (b < PREP_DINV_B + PREP_B2FS_B) {
        int t = (b - PREP_DINV_B) * 256 + threadIdx.x;   // < NN*128/4
        float w = 1.0f / sqrtf((float)cur[t >> 5] + 1.0f);
        float4 v = reinterpret_cast<const float4*>(x)[t];
        ushort4 o;
        o.x = f2bf(v.x * w); o.y = f2bf(v.y * w);
        o.z = f2bf(v.z * w); o.w = f2bf(v.w * w);
        reinterpret_cast<ushort4*>(U)[t] = o;
    } else {
        int t = (b - PREP_DINV_B - PREP_B2FS_B) * 256 + threadIdx.x;
        if (t < 1024)      wt_pack(Wt1, W1, 256, t);
        else if (t < 2048) wt_pack(Wt2, W2, 128, t - 1024);
        else if (t < 2304) wt_pack(Wt3, W3, 64, t - 2048);
        else if (t < PREP_WT_T) wt_pack(Wt4, W4, 32, t - 2304);
    }
}

// Pull aggregation over PRE-SCALED bf16 payload H' (= H*dinv), fp32 accumulate:
//   out[i,:] = dinv_i * (H'[i,:] + sum_{e: dst=i} H'[src_e,:])  (+bias, relu)
// thread = (node, 8 features): 16B uint4 gathers; 4-edge unroll; pure adds.
// Rows are coarsely src-sorted -> gathers stream ascending through payload.
template <int D, int BR, int OUTBF>
__global__ __launch_bounds__(256) void k_pullq(void* __restrict__ outv,
                                               const unsigned short* __restrict__ Hb,
                                               const unsigned short* __restrict__ pcsr,
                                               const int* __restrict__ deg,
                                               const float* __restrict__ dinv,
                                               const float* __restrict__ bias,
                                               int n) {
    constexpr int TPN = D / 8;               // threads per node
    constexpr int NPB = 256 / TPN;           // nodes per block
    const int node = blockIdx.x * NPB + threadIdx.x / TPN;
    const int f8 = threadIdx.x % TPN;
    if (node >= n) return;
    const float wd = dinv[node];
    const uint4* __restrict__ Hv = (const uint4*)Hb;  // 8 bf16 per uint4
    uint4 ps = Hv[(long)node * TPN + f8];             // self term, pre-scaled
    float a0 = bflo(ps.x), a1 = bfhi(ps.x);
    float a2 = bflo(ps.y), a3 = bfhi(ps.y);
    float a4 = bflo(ps.z), a5 = bfhi(ps.z);
    float a6 = bflo(ps.w), a7 = bfhi(ps.w);
    int dg = deg[node];
    if (dg > CAP) dg = CAP;
    const unsigned short* __restrict__ row = pcsr + (long)node * CAP;
    int j = 0;
    for (; j + 4 <= dg; j += 4) {
        ushort4 ii = *(const ushort4*)(row + j);
        uint4 p0 = Hv[(long)ii.x * TPN + f8];
        uint4 p1 = Hv[(long)ii.y * TPN + f8];
        uint4 p2 = Hv[(long)ii.z * TPN + f8];
        uint4 p3 = Hv[(long)ii.w * TPN + f8];
        a0 += bflo(p0.x) + bflo(p1.x) + bflo(p2.x) + bflo(p3.x);
        a1 += bfhi(p0.x) + bfhi(p1.x) + bfhi(p2.x) + bfhi(p3.x);
        a2 += bflo(p0.y) + bflo(p1.y) + bflo(p2.y) + bflo(p3.y);
        a3 += bfhi(p0.y) + bfhi(p1.y) + bfhi(p2.y) + bfhi(p3.y);
        a4 += bflo(p0.z) + bflo(p1.z) + bflo(p2.z) + bflo(p3.z);
        a5 += bfhi(p0.z) + bfhi(p1.z) + bfhi(p2.z) + bfhi(p3.z);
        a6 += bflo(p0.w) + bflo(p1.w) + bflo(p2.w) + bflo(p3.w);
        a7 += bfhi(p0.w) + bfhi(p1.w) + bfhi(p2.w) + bfhi(p3.w);
    }
    for (; j < dg; ++j) {
        uint4 p = Hv[(long)row[j] * TPN + f8];
        a0 += bflo(p.x); a1 += bfhi(p.x);
        a2 += bflo(p.y); a3 += bfhi(p.y);
        a4 += bflo(p.z); a5 += bfhi(p.z);
        a6 += bflo(p.w); a7 += bfhi(p.w);
    }
    a0 *= wd; a1 *= wd; a2 *= wd; a3 *= wd;
    a4 *= wd; a5 *= wd; a6 *= wd; a7 *= wd;
    if (BR) {
        float4 b0 = ((const float4*)bias)[2 * f8];
        float4 b1 = ((const float4*)bias)[2 * f8 + 1];
        a0 = fmaxf(a0 + b0.x, 0.f); a1 = fmaxf(a1 + b0.y, 0.f);
        a2 = fmaxf(a2 + b0.z, 0.f); a3 = fmaxf(a3 + b0.w, 0.f);
        a4 = fmaxf(a4 + b1.x, 0.f); a5 = fmaxf(a5 + b1.y, 0.f);
        a6 = fmaxf(a6 + b1.z, 0.f); a7 = fmaxf(a7 + b1.w, 0.f);
    }
    if (OUTBF) {
        uint4 o;
        o.x = packbf(a0, a1); o.y = packbf(a2, a3);
        o.z = packbf(a4, a5); o.w = packbf(a6, a7);
        ((uint4*)outv)[(long)node * TPN + f8] = o;
    } else {
        float4 o0; o0.x = a0; o0.y = a1; o0.z = a2; o0.w = a3;
        float4 o1; o1.x = a4; o1.y = a5; o1.z = a6; o1.w = a7;
        ((float4*)outv)[(long)node * (D / 4) + 2 * f8] = o0;
        ((float4*)outv)[(long)node * (D / 4) + 2 * f8 + 1] = o1;
    }
}

// MFMA GEMM: out[N,dout] = Xb[N,DIN](bf16) @ W (via Wt packing), fp32 acc.
// wave = 16 rows x NT*16 cols; block = 4 waves = 64 rows. No LDS.
// SCALE: multiply output row m by dinv[m] (pre-scaling for the next pull).
template <int DIN, int NT, int BIAS_RELU, int OUTBF, int SCALE>
__global__ __launch_bounds__(256) void k_mm(const unsigned short* __restrict__ Xb,
                                            const unsigned short* __restrict__ Wt,
                                            const float* __restrict__ bias,
                                            const float* __restrict__ dinv,
                                            void* __restrict__ outv,
                                            int N, int dout) {
    constexpr int KI = DIN / 32;
    const int lane = threadIdx.x & 63;
    const int wv   = threadIdx.x >> 6;
    const int m0   = blockIdx.x * 64 + wv * 16;
    const int n0   = blockIdx.y * (NT * 16);
    const int l15  = lane & 15;
    const int quad = lane >> 4;

    int mrow = m0 + l15;
    if (mrow >= N) mrow = N - 1;                     // clamped loads; stores guarded
    const unsigned short* xp = Xb + (long)mrow * DIN + quad * 8;
    const unsigned short* wp = Wt + (long)(n0 + l15) * 32 + quad * 8;

    fv4 acc[NT];
#pragma unroll
    for (int t = 0; t < NT; ++t) acc[t] = (fv4){0.f, 0.f, 0.f, 0.f};

#pragma unroll
    for (int kc = 0; kc < KI; ++kc) {
        bfv8 a = *(const bfv8*)(xp + kc * 32);
#pragma unroll
        for (int t = 0; t < NT; ++t) {
            bfv8 b = *(const bfv8*)(wp + (long)kc * dout * 32 + t * 16 * 32);
            acc[t] = __builtin_amdgcn_mfma_f32_16x16x32_bf16(a, b, acc[t], 0, 0, 0);
        }
    }

    float sc[4];
#pragma unroll
    for (int r = 0; r < 4; ++r) {
        int m = m0 + quad * 4 + r;
        sc[r] = SCALE ? dinv[(m < N) ? m : (N - 1)] : 1.0f;
    }

#pragma unroll
    for (int t = 0; t < NT; ++t) {
        const int col = n0 + t * 16 + l15;
        float bb = BIAS_RELU ? bias[col] : 0.f;
#pragma unroll
        for (int r = 0; r < 4; ++r) {
            int m = m0 + quad * 4 + r;
            if (m < N) {
                float v = acc[t][r];
                if (BIAS_RELU) v = fmaxf(v + bb, 0.f);
                if (SCALE) v *= sc[r];
                if (OUTBF)
                    ((unsigned short*)outv)[(long)m * dout + col] = f2bf(v);
                else
                    ((float*)outv)[(long)m * dout + col] = v;
            }
        }
    }
}

extern "C" void kernel_launch(void* const* d_in, const int* in_sizes, int n_in,
                              void* d_out, int out_size, void* d_ws, size_t ws_size,
                              hipStream_t stream) {
    const int N = NN;
    const int E = in_sizes[1] / 2;

    const float* x  = (const float*)d_in[0];
    const int* ei   = (const int*)d_in[1];
    const int* src  = ei;
    const int* dst  = ei + E;
    const float* W1 = (const float*)d_in[2];
    const float* b1 = (const float*)d_in[3];
    const float* W2 = (const float*)d_in[4];
    const float* b2 = (const float*)d_in[5];
    const float* W3 = (const float*)d_in[6];
    const float* b3 = (const float*)d_in[7];
    const float* W4 = (const float*)d_in[8];
    const float* b4 = (const float*)d_in[9];

    float* dinv = (float*)d_ws;                       // N f32
    int*   cur  = (int*)(dinv + N);                   // N i32
    unsigned short* U    = (unsigned short*)(cur + N);        // N*256 bf16
    unsigned short* V    = U + (long)N * 256;                 // N*256 bf16
    unsigned short* pcsr = V + (long)N * 256;                 // N*CAP ushort
    unsigned short* Wt1  = pcsr + (long)N * CAP;              // 128*256
    unsigned short* Wt2  = Wt1 + 128 * 256;                   // 256*128
    unsigned short* Wt3  = Wt2 + 256 * 128;                   // 128*64
    unsigned short* Wt4  = Wt3 + 128 * 64;                    // 64*32

    // CSR-build scratch: lives inside U (dead until k_prep overwrites it).
    // seg: 256 slices x 196 buckets x 96 cap x 4B = 19.27MB  (U = 25.6MB)
    uint32_t* seg  = (uint32_t*)U;
    int*      cnts = (int*)(seg + (long)NSLICEA * NB * CAPSEG);  // 256*196 i32

    (void)n_in; (void)out_size; (void)ws_size;

    const int GX = (N + 63) / 64;                     // 782 row-blocks

    // ---- CSR build (2-phase bucketed, binned rows) + fused prep
    k_bucket<<<NSLICEA, 256, 0, stream>>>(seg, cnts, src, dst, E);
    k_build<<<NB, 256, 0, stream>>>(pcsr, cur, seg, cnts, N);
    k_prep<<<PREP_DINV_B + PREP_B2FS_B + PREP_WT_B, 256, 0, stream>>>(
        dinv, cur, U, x, Wt1, W1, Wt2, W2, Wt3, W3, Wt4, W4);

    // ---- Layer 1: P0b = Prop(x') [N,128] -> V; H1b = relu(P0b@W1+b1) [N,256] -> U
    k_pullq<128, 0, 1><<<(N + 15) / 16, 256, 0, stream>>>(V, U, pcsr, cur, dinv, nullptr, N);
    k_mm<128, 4, 1, 1, 0><<<dim3(GX, 4), 256, 0, stream>>>(V, Wt1, b1, dinv, U, N, 256);

    // ---- Layer 2: T2' = (H1b@W2)*dinv [N,128] -> V; H2b = relu(Prop+b2) -> U
    k_mm<256, 4, 0, 1, 1><<<dim3(GX, 2), 256, 0, stream>>>(U, Wt2, nullptr, dinv, V, N, 128);
    k_pullq<128, 1, 1><<<(N + 15) / 16, 256, 0, stream>>>(U, V, pcsr, cur, dinv, b2, N);

    // ---- Layer 3: T3' = (H2b@W3)*dinv [N,64] -> V; H3b = relu(Prop+b3) -> U
    k_mm<128, 4, 0, 1, 1><<<dim3(GX, 1), 256, 0, stream>>>(U, Wt3, nullptr, dinv, V, N, 64);
    k_pullq<64, 1, 1><<<(N + 31) / 32, 256, 0, stream>>>(U, V, pcsr, cur, dinv, b3, N);

    // ---- Layer 4: T4' = (H3b@W4)*dinv [N,32] -> V; out = relu(Prop+b4) fp32
    k_mm<64, 2, 0, 1, 1><<<dim3(GX, 1), 256, 0, stream>>>(U, Wt4, nullptr, dinv, V, N, 32);
    k_pullq<32, 1, 0><<<(N + 63) / 64, 256, 0, stream>>>(d_out, V, pcsr, cur, dinv, b4, N);
}